// Round 7
// baseline (1785.226 us; speedup 1.0000x reference)
//
#include <hip/hip_runtime.h>

// RecurrentSNN: B=256, T=1024, F=64, H=512, O=64
// out = concat(mem_rec [B,T,O], spk_rec [B,T,O]) f32.
//
// Round-7: fix both split kernels' occupancy/register regimes.
//  K1 snn_cur1: waves_per_eu(2,2) -> 256-reg budget (round-6's (512,4) bound
//    = 128 regs pushed win into AGPRs -> per-FMA AGPR traffic, 272us/chunk).
//    Ping-pong x-row prefetch pipeline (two 16-float4 banks + win = ~207 VGPR).
//  K2 snn_rec: 1024 threads (16 waves, 4/SIMD) via CHAIN-split, not h-split:
//    wave pair (tw, tw+8): role 0 computes chains a0,a1 (k=4q,4q+1), role 1
//    computes a2,a3 (k=4q+2,4q+3) -- independent accumulators, so arithmetic
//    is EXACTLY round-6's. red[s][o][role] holds (a0+a1) and (a2+a3);
//    reducer does co += (lo + hi) = ((a0+a1)+(a2+a3)) -- exact tree.
//    L1STEP duplicated bitwise in twin waves. Waves 0/1 both replicate the
//    memo chain; wave0 stores mem_rec, wave1 stores spk_rec.
// All chains bit-identical to rounds 1-6 (absmax must be 0.04394531).

namespace {
constexpr int kB = 256;
constexpr int kT = 1024;
constexpr int kF = 64;
constexpr int kH = 512;
constexpr int kO = 64;
constexpr float kBeta = 0.9f;
constexpr float kThresh = 1.0f;
}  // namespace

#define PIN8(p)                                                            \
  asm volatile("" : "+v"((p)[0]), "+v"((p)[1]), "+v"((p)[2]),              \
                    "+v"((p)[3]), "+v"((p)[4]), "+v"((p)[5]),              \
                    "+v"((p)[6]), "+v"((p)[7]))

#define BARRIER() asm volatile("s_waitcnt lgkmcnt(0)\n\ts_barrier" ::: "memory")

// ======================= K1: cur1 = x @ W_in^T + b_in ======================
#define FMA4(v, q)                                                         \
  c0 = fmaf((v).x, win[4 * (q) + 0], c0);                                  \
  c1 = fmaf((v).y, win[4 * (q) + 1], c1);                                  \
  c2 = fmaf((v).z, win[4 * (q) + 2], c2);                                  \
  c3 = fmaf((v).w, win[4 * (q) + 3], c3);

__global__ __launch_bounds__(512)
__attribute__((amdgpu_waves_per_eu(2, 2)))
void snn_cur1(const float* __restrict__ x, const float* __restrict__ W_in,
              const float* __restrict__ b_in, float* __restrict__ cur1,
              int t0, int ntc) {
  const int lane = threadIdx.x & 63;
  const int s = threadIdx.x >> 6;
  const int h = s * 64 + lane;
  const int bpb = ntc >> 7;  // blocks per batch element
  const int b = blockIdx.x / bpb;
  const int tcb = (blockIdx.x - b * bpb) * 128;

  float win[kF];
  {
    const float4* wiv = reinterpret_cast<const float4*>(W_in) + h * 16;
#pragma unroll
    for (int q = 0; q < 16; ++q) {
      const float4 v = wiv[q];
      win[4 * q + 0] = v.x; win[4 * q + 1] = v.y;
      win[4 * q + 2] = v.z; win[4 * q + 3] = v.w;
    }
  }
  float bin_h = b_in[h];
  PIN8(win + 0);  PIN8(win + 8);  PIN8(win + 16); PIN8(win + 24);
  PIN8(win + 32); PIN8(win + 40); PIN8(win + 48); PIN8(win + 56);
  asm volatile("" : "+v"(bin_h));

  const float* xb = x + ((size_t)b * kT + t0 + tcb) * kF;
  float* cb = cur1 + ((size_t)b * ntc + tcb) * (size_t)kH + h;

  // two x-row banks (ping-pong prefetch), 16 float4 each
  float4 a0, a1, a2, a3, a4, a5, a6, a7, a8, a9, a10, a11, a12, a13, a14, a15;
  float4 e0, e1, e2, e3, e4, e5, e6, e7, e8, e9, e10, e11, e12, e13, e14, e15;

#define LDB(bank, i)                                                       \
  do {                                                                     \
    const float4* p = reinterpret_cast<const float4*>(xb + (size_t)(i) * kF); \
    bank##0 = p[0]; bank##1 = p[1]; bank##2 = p[2]; bank##3 = p[3];        \
    bank##4 = p[4]; bank##5 = p[5]; bank##6 = p[6]; bank##7 = p[7];        \
    bank##8 = p[8]; bank##9 = p[9]; bank##10 = p[10]; bank##11 = p[11];    \
    bank##12 = p[12]; bank##13 = p[13]; bank##14 = p[14]; bank##15 = p[15]; \
  } while (0)

#define ROW(bank, i)                                                       \
  do {                                                                     \
    float c0 = bin_h, c1 = 0.0f, c2 = 0.0f, c3 = 0.0f;                     \
    FMA4(bank##0, 0) FMA4(bank##1, 1) FMA4(bank##2, 2) FMA4(bank##3, 3)    \
    FMA4(bank##4, 4) FMA4(bank##5, 5) FMA4(bank##6, 6) FMA4(bank##7, 7)    \
    FMA4(bank##8, 8) FMA4(bank##9, 9) FMA4(bank##10, 10)                   \
    FMA4(bank##11, 11) FMA4(bank##12, 12) FMA4(bank##13, 13)               \
    FMA4(bank##14, 14) FMA4(bank##15, 15)                                  \
    cb[(size_t)(i) * kH] = (c0 + c1) + (c2 + c3);                          \
  } while (0)

  LDB(a, 0);
  for (int i = 0; i < 128; i += 2) {
    LDB(e, i + 1);                       // prefetch odd row
    ROW(a, i);                           // compute even row
    LDB(a, (i + 2 < 128) ? i + 2 : 127); // prefetch next even row
    ROW(e, i + 1);                       // compute odd row
  }
#undef LDB
#undef ROW
}

// ======================= K2: the two recurrences ===========================
// 1024 threads = 16 waves: wave w -> slice tw = w&7, role = w>>3.
// Twin waves (tw, tw+8) duplicate the layer-1 state for h = tw*64+lane
// bitwise; layer-2 chains split by role (a0,a1 vs a2,a3) -- exact.
#define SPK(k)                                                             \
  __int_as_float(__builtin_amdgcn_readlane(__float_as_int(rst1), (k)))

#define L1STEP(PF)                                                         \
  do {                                                                     \
    mem1 = kBeta * mem1 + (PF)-rst1;                                       \
    const bool p = mem1 > kThresh;                                         \
    rst1 = p ? 1.0f : 0.0f;                                                \
  } while (0)

#define LAYER2(buf)                                                        \
  do {                                                                     \
    float alo = 0.0f, ahi = 0.0f;                                          \
    _Pragma("unroll") for (int q = 0; q < 16; ++q) {                       \
      alo = fmaf(SPK(4 * q + kbase), wlo[q], alo);                         \
      ahi = fmaf(SPK(4 * q + kbase + 1), whi[q], ahi);                     \
    }                                                                      \
    red[(buf)][tw][o][role] = alo + ahi;                                   \
  } while (0)

#define ISSUE_RR(buf)                                                      \
  do {                                                                     \
    rr0 = *reinterpret_cast<const float2*>(&red[(buf)][0][o][0]);          \
    rr1 = *reinterpret_cast<const float2*>(&red[(buf)][1][o][0]);          \
    rr2 = *reinterpret_cast<const float2*>(&red[(buf)][2][o][0]);          \
    rr3 = *reinterpret_cast<const float2*>(&red[(buf)][3][o][0]);          \
    rr4 = *reinterpret_cast<const float2*>(&red[(buf)][4][o][0]);          \
    rr5 = *reinterpret_cast<const float2*>(&red[(buf)][5][o][0]);          \
    rr6 = *reinterpret_cast<const float2*>(&red[(buf)][6][o][0]);          \
    rr7 = *reinterpret_cast<const float2*>(&red[(buf)][7][o][0]);          \
  } while (0)

#define CONSUME(tt)                                                        \
  do {                                                                     \
    float co = bout_o;                                                     \
    co += (rr0.x + rr0.y); co += (rr1.x + rr1.y);                          \
    co += (rr2.x + rr2.y); co += (rr3.x + rr3.y);                          \
    co += (rr4.x + rr4.y); co += (rr5.x + rr5.y);                          \
    co += (rr6.x + rr6.y); co += (rr7.x + rr7.y);                          \
    memo = kBeta * memo + co - rsto;                                       \
    const float so = (memo > kThresh) ? 1.0f : 0.0f;                       \
    rsto = so;                                                             \
    if (w == 0) om[(size_t)(tt) * kO] = memo;                              \
    else os[(size_t)(tt) * kO] = so;                                       \
  } while (0)

__global__ __launch_bounds__(1024)
void snn_rec(const float* __restrict__ cur1, const float* __restrict__ W_out,
             const float* __restrict__ b_out, float* __restrict__ out,
             float* __restrict__ state, int t0, int ntc) {
  const int b = blockIdx.x;
  const int j = threadIdx.x;
  const int lane = j & 63;
  const int w = j >> 6;
  const int tw = w & 7;     // h-slice
  const int role = w >> 3;  // 0: chains a0,a1 ; 1: chains a2,a3
  const int o = lane;
  const int h = tw * 64 + lane;
  const int kbase = role * 2;

  __shared__ float red[2][8][64][2];  // [buf][slice][o][role-half]

  // role-half of W_out[o][tw*64 + 4q + kbase + {0,1}]
  float wlo[16], whi[16];
  {
    const float4* wov =
        reinterpret_cast<const float4*>(W_out) + o * (kH / 4) + tw * 16;
#pragma unroll
    for (int q = 0; q < 16; ++q) {
      const float4 v = wov[q];
      wlo[q] = role ? v.z : v.x;
      whi[q] = role ? v.w : v.y;
    }
  }
  float bout_o = b_out[o];
  PIN8(wlo + 0); PIN8(wlo + 8); PIN8(whi + 0); PIN8(whi + 8);
  asm volatile("" : "+v"(bout_o));

  float* m1s = state;                  // [kB*kH]
  float* r1s = state + kB * kH;        // [kB*kH]
  float* mos = state + 2 * kB * kH;    // [kB*kO]
  float* ros = mos + kB * kO;          // [kB*kO]
  const int idx1 = b * kH + h;
  const int idxo = b * kO + o;

  float mem1 = 0.0f, rst1 = 0.0f, memo = 0.0f, rsto = 0.0f;
  if (t0 != 0) {
    mem1 = m1s[idx1];
    rst1 = r1s[idx1];
    if (w < 2) { memo = mos[idxo]; rsto = ros[idxo]; }
  }

  const float* cp = cur1 + (size_t)b * ntc * kH + h;
  float* om = out + ((size_t)b * kT + t0) * kO + o;
  float* os = om + (size_t)kB * kT * kO;

  float2 rr0, rr1, rr2, rr3, rr4, rr5, rr6, rr7;
  float pfa = cp[0];
  float pfb = cp[(size_t)1 * kH];

  for (int tc = 0; tc < ntc; tc += 2) {
    // ---- even step tc (buf 0) ----
    L1STEP(pfa);
    {
      const int tp = (tc + 2 < ntc) ? tc + 2 : ntc - 1;
      pfa = cp[(size_t)tp * kH];  // vmcnt-domain, survives the barrier
    }
    LAYER2(0);
    if (j < 128 && tc != 0) CONSUME(tc - 1);
    BARRIER();
    if (j < 128) ISSUE_RR(0);

    // ---- odd step tc+1 (buf 1) ----
    L1STEP(pfb);
    {
      const int tp = (tc + 3 < ntc) ? tc + 3 : ntc - 1;
      pfb = cp[(size_t)tp * kH];
    }
    LAYER2(1);
    if (j < 128) CONSUME(tc);
    BARRIER();
    if (j < 128) ISSUE_RR(1);
  }
  if (j < 128) CONSUME(ntc - 1);

  // ---- save state (role 0 owns layer-1 state; wave 0 owns layer-2) ----
  if (role == 0) { m1s[idx1] = mem1; r1s[idx1] = rst1; }
  if (w == 0) { mos[idxo] = memo; ros[idxo] = rsto; }
}

// ======================= fallback (round-5, proven) ========================
#define BITF(k) ((((k) < 32 ? (mlo >> (k)) : (mhi >> ((k)-32))) & 1u) \
                 ? 1.0f : 0.0f)

__global__ __launch_bounds__(256)
void warm_x_kernel(const float4* __restrict__ p, int n4) {
  float acc = 0.0f;
  for (int i = blockIdx.x * blockDim.x + threadIdx.x; i < n4;
       i += gridDim.x * blockDim.x) {
    const float4 v = p[i];
    acc += v.x + v.y + v.z + v.w;
  }
  asm volatile("" ::"v"(acc));
}

__global__ __launch_bounds__(512)
__attribute__((amdgpu_waves_per_eu(2, 2)))
void snn_fused5(const float* __restrict__ x, const float* __restrict__ W_in,
                const float* __restrict__ b_in,
                const float* __restrict__ W_out,
                const float* __restrict__ b_out, float* __restrict__ out) {
  const int b = blockIdx.x;
  const int j = threadIdx.x;
  const int o = j & 63;
  const int s = j >> 6;
  __shared__ float red[2][8][64];
  float win[kF];
  {
    const float4* wiv = reinterpret_cast<const float4*>(W_in) + j * 16;
#pragma unroll
    for (int q = 0; q < 16; ++q) {
      const float4 v = wiv[q];
      win[4 * q] = v.x; win[4 * q + 1] = v.y;
      win[4 * q + 2] = v.z; win[4 * q + 3] = v.w;
    }
  }
  float wout[64];
  {
    const float4* wov =
        reinterpret_cast<const float4*>(W_out) + o * 128 + s * 16;
#pragma unroll
    for (int q = 0; q < 16; ++q) {
      const float4 v = wov[q];
      wout[4 * q] = v.x; wout[4 * q + 1] = v.y;
      wout[4 * q + 2] = v.z; wout[4 * q + 3] = v.w;
    }
  }
  float bin_j = b_in[j];
  float bout_o = b_out[o];
  PIN8(win + 0);  PIN8(win + 8);  PIN8(win + 16); PIN8(win + 24);
  PIN8(win + 32); PIN8(win + 40); PIN8(win + 48); PIN8(win + 56);
  PIN8(wout + 0);  PIN8(wout + 8);  PIN8(wout + 16); PIN8(wout + 24);
  PIN8(wout + 32); PIN8(wout + 40); PIN8(wout + 48); PIN8(wout + 56);
  asm volatile("" : "+v"(bin_j), "+v"(bout_o));
  float mem1 = 0.0f, rst1 = 0.0f, memo = 0.0f, rsto = 0.0f;
  unsigned long long mask = 0ull;
  const float4* xv = reinterpret_cast<const float4*>(x + (size_t)b * kT * kF);
  float* out_mem = out + (size_t)b * kT * kO + o;
  float* out_spk = out_mem + (size_t)kB * kT * kO;
  float4 x0, x1, x2, x3, x4, x5, x6, x7, x8, x9, x10, x11, x12, x13, x14, x15;
#define LOADX(tt)                                                          \
  do {                                                                     \
    const float4* xp = xv + (size_t)(tt) * 16;                             \
    x0 = xp[0]; x1 = xp[1]; x2 = xp[2]; x3 = xp[3];                        \
    x4 = xp[4]; x5 = xp[5]; x6 = xp[6]; x7 = xp[7];                        \
    x8 = xp[8]; x9 = xp[9]; x10 = xp[10]; x11 = xp[11];                    \
    x12 = xp[12]; x13 = xp[13]; x14 = xp[14]; x15 = xp[15];                \
  } while (0)
#define L1Q(q)                                                             \
  c0 = fmaf(x##q.x, win[4 * q + 0], c0);                                   \
  c1 = fmaf(x##q.y, win[4 * q + 1], c1);                                   \
  c2 = fmaf(x##q.z, win[4 * q + 2], c2);                                   \
  c3 = fmaf(x##q.w, win[4 * q + 3], c3);
#define LAYER1F()                                                          \
  do {                                                                     \
    float c0 = bin_j, c1 = 0.0f, c2 = 0.0f, c3 = 0.0f;                     \
    L1Q(0) L1Q(1) L1Q(2) L1Q(3) L1Q(4) L1Q(5) L1Q(6) L1Q(7)                \
    L1Q(8) L1Q(9) L1Q(10) L1Q(11) L1Q(12) L1Q(13) L1Q(14) L1Q(15)          \
    const float cur1v = (c0 + c1) + (c2 + c3);                             \
    mem1 = kBeta * mem1 + cur1v - rst1;                                    \
    const bool p = mem1 > kThresh;                                         \
    mask = __ballot(p);                                                    \
    rst1 = p ? 1.0f : 0.0f;                                                \
  } while (0)
#define L2QS(q)                                                            \
  {                                                                        \
    const float f0 = ((mlo >> (4 * (q) + 0)) & 1u) ? 1.0f : 0.0f;          \
    const float f1 = ((mlo >> (4 * (q) + 1)) & 1u) ? 1.0f : 0.0f;          \
    const float f2 = ((mlo >> (4 * (q) + 2)) & 1u) ? 1.0f : 0.0f;          \
    const float f3 = ((mlo >> (4 * (q) + 3)) & 1u) ? 1.0f : 0.0f;          \
    a0 = fmaf(f0, wout[4 * (q) + 0], a0);                                  \
    a1 = fmaf(f1, wout[4 * (q) + 1], a1);                                  \
    a2 = fmaf(f2, wout[4 * (q) + 2], a2);                                  \
    a3 = fmaf(f3, wout[4 * (q) + 3], a3);                                  \
  }
#define L2E(acc, q, i)                                                     \
  acc = acc + __uint_as_float(                                             \
      (unsigned)__builtin_amdgcn_sbfe((int)vmhi, 4 * (q) + (i)-32, 1) &    \
      __float_as_uint(wout[4 * (q) + (i)]));
#define L2QV(q)                                                            \
  { L2E(a0, q, 0) L2E(a1, q, 1) L2E(a2, q, 2) L2E(a3, q, 3) }
#define LAYER2F(buf)                                                       \
  do {                                                                     \
    const unsigned mlo = (unsigned)mask;                                   \
    unsigned vmhi = (unsigned)(mask >> 32);                                \
    asm volatile("" : "+v"(vmhi));                                         \
    float a0 = 0.0f, a1 = 0.0f, a2 = 0.0f, a3 = 0.0f;                      \
    L2QS(0) L2QS(1) L2QS(2) L2QS(3) L2QS(4) L2QS(5) L2QS(6) L2QS(7)        \
    L2QV(8) L2QV(9) L2QV(10) L2QV(11) L2QV(12) L2QV(13) L2QV(14) L2QV(15)  \
    red[(buf)][s][o] = (a0 + a1) + (a2 + a3);                              \
  } while (0)
  LOADX(0);
  LAYER1F();
  LOADX(1);
  for (int t = 1; t < kT; ++t) {
    LAYER2F((t - 1) & 1);
    BARRIER();
    float r0, r1, r2, r3, r4, r5, r6, r7;
    const int buf = (t - 1) & 1;
    if (s == 0) {
      r0 = red[buf][0][o]; r1 = red[buf][1][o];
      r2 = red[buf][2][o]; r3 = red[buf][3][o];
      r4 = red[buf][4][o]; r5 = red[buf][5][o];
      r6 = red[buf][6][o]; r7 = red[buf][7][o];
    }
    LAYER1F();
    const int tn = (t + 1 < kT) ? (t + 1) : (kT - 1);
    LOADX(tn);
    if (s == 0) {
      float co = bout_o;
      co += r0; co += r1; co += r2; co += r3;
      co += r4; co += r5; co += r6; co += r7;
      memo = kBeta * memo + co - rsto;
      const float so = (memo > kThresh) ? 1.0f : 0.0f;
      rsto = so;
      out_mem[(t - 1) * kO] = memo;
      out_spk[(t - 1) * kO] = so;
    }
  }
  LAYER2F((kT - 1) & 1);
  BARRIER();
  if (s == 0) {
    const int buf = (kT - 1) & 1;
    float co = bout_o;
    co += red[buf][0][o]; co += red[buf][1][o];
    co += red[buf][2][o]; co += red[buf][3][o];
    co += red[buf][4][o]; co += red[buf][5][o];
    co += red[buf][6][o]; co += red[buf][7][o];
    memo = kBeta * memo + co - rsto;
    const float so = (memo > kThresh) ? 1.0f : 0.0f;
    out_mem[(kT - 1) * kO] = memo;
    out_spk[(kT - 1) * kO] = so;
  }
}

// ======================= host ==============================================
extern "C" void kernel_launch(void* const* d_in, const int* in_sizes, int n_in,
                              void* d_out, int out_size, void* d_ws,
                              size_t ws_size, hipStream_t stream) {
  const float* x = (const float*)d_in[0];
  const float* W_in = (const float*)d_in[1];
  const float* b_in = (const float*)d_in[2];
  const float* W_out = (const float*)d_in[3];
  const float* b_out = (const float*)d_in[4];
  float* out = (float*)d_out;

  const size_t state_bytes = ((size_t)2 * kB * kH + 2 * kB * kO) * 4;
  int nch = 0;
  for (int c : {4, 8}) {
    const size_t need = (size_t)kB * (kT / c) * kH * 4 + state_bytes;
    if (need <= ws_size) { nch = c; break; }
  }

  if (nch) {
    const int ntc = kT / nch;
    float* cur1 = (float*)d_ws;
    float* state = cur1 + (size_t)kB * ntc * kH;
    const int g1 = kB * (ntc / 128);
    for (int c = 0; c < nch; ++c) {
      hipLaunchKernelGGL(snn_cur1, dim3(g1), dim3(512), 0, stream,
                         x, W_in, b_in, cur1, c * ntc, ntc);
      hipLaunchKernelGGL(snn_rec, dim3(kB), dim3(1024), 0, stream,
                         cur1, W_out, b_out, out, state, c * ntc, ntc);
    }
  } else {
    const int n4 = kB * kT * kF / 4;
    hipLaunchKernelGGL(warm_x_kernel, dim3(1024), dim3(256), 0, stream,
                       (const float4*)x, n4);
    hipLaunchKernelGGL(snn_fused5, dim3(kB), dim3(512), 0, stream,
                       x, W_in, b_in, W_out, b_out, out);
  }
}